// Round 13
// baseline (1275.422 us; speedup 1.0000x reference)
//
#include <hip/hip_runtime.h>
#include <math.h>

// Problem constants
#define B_    256
#define NPTS  1024
#define T_    50

// ---------------------------------------------------------------------------
// ws layout (bytes):
//   [0,       786432)   wp   f32 [64][3][256][4]  packed W_hh (round-7 layout)
//   [786432,  1310720)  henc u32 [256][512]       (f32-bit maxpool via atomicMax)
// ---------------------------------------------------------------------------

__global__ __launch_bounds__(256) void prep_kernel(
    const float* __restrict__ whh, float* __restrict__ wp,
    unsigned* __restrict__ henc) {
  int idx = blockIdx.x * 256 + threadIdx.x;   // grid 768*256 = 196608
  if (idx < 196608) {
    int c = idx & 3;
    int r = idx >> 2;            // (k4*3+j)*256 + t
    int t2 = r & 255;
    int q = r >> 8;              // k4*3 + j
    int j = q % 3;
    int k4 = q / 3;
    wp[idx] = whh[(j * 256 + t2) * 256 + (k4 * 4 + c)];
  }
  if (idx < 131072) henc[idx] = 0u;           // bits 0 == +0.0f; relu>=0 valid
}

// ---------------------------------------------------------------------------
// Encoder -- R11 winner verbatim (two tiles per pass; w3 sK$ re-streams
// halved 8->4; all FMA chains keep R4 seed + ascending-k order).
// ---------------------------------------------------------------------------
__global__ __launch_bounds__(1024) void enc_kernel(
    const float* __restrict__ data,
    const float* __restrict__ w1, const float* __restrict__ b1,
    const float* __restrict__ w2, const float* __restrict__ b2,
    const float* __restrict__ w3, const float* __restrict__ b3,
    unsigned* __restrict__ henc) {
  __shared__ float h2t[2][128][66];
  const int t = threadIdx.x;
  const int b = blockIdx.x >> 1;
  const int half = blockIdx.x & 1;
  const int lane = t & 63;
  const int wv = __builtin_amdgcn_readfirstlane(t >> 6);   // wave id 0..15

  float m[32];
#pragma unroll
  for (int o = 0; o < 32; ++o) m[o] = 0.0f;                // relu via max w/ 0
  const float* __restrict__ w3b = w3 + wv * 32;

#pragma unroll 1
  for (int pair = 0; pair < 4; ++pair) {
#pragma unroll
    for (int tt = 0; tt < 2; ++tt) {                       // R4 phase-1 x2
      const int ptg = b * NPTS + half * 512 + (pair * 2 + tt) * 64 + lane;
      const float x0 = data[ptg * 3], x1 = data[ptg * 3 + 1], x2 = data[ptg * 3 + 2];
      float a[8];
#pragma unroll
      for (int c = 0; c < 8; ++c) a[c] = b2[wv * 8 + c];   // s_load
#pragma unroll 4
      for (int j = 0; j < 64; ++j) {                       // w1/b1 uniform
        float hj = fmaf(x0, w1[j], fmaf(x1, w1[64 + j], fmaf(x2, w1[128 + j], b1[j])));
        hj = fmaxf(hj, 0.0f);
        const float* __restrict__ w2r = w2 + j * 128 + wv * 8;  // s_load x8
#pragma unroll
        for (int c = 0; c < 8; ++c) a[c] = fmaf(hj, w2r[c], a[c]);
      }
#pragma unroll
      for (int c = 0; c < 8; ++c) h2t[tt][wv * 8 + c][lane] = fmaxf(a[c], 0.0f);
    }
    __syncthreads();

    float acc0[32], acc1[32];
#pragma unroll
    for (int o = 0; o < 32; ++o) {
      acc0[o] = b3[wv * 32 + o];                           // s_load seed (R4)
      acc1[o] = acc0[o];                                   // same b3 value
    }
#pragma unroll 4
    for (int k = 0; k < 128; ++k) {
      const float hk0 = h2t[0][k][lane];                   // ds_read_b32
      const float hk1 = h2t[1][k][lane];                   // ds_read_b32
      const float* __restrict__ wr = w3b + k * 512;        // ONE s_load row
#pragma unroll
      for (int o = 0; o < 32; ++o) {
        const float w = wr[o];
        acc0[o] = fmaf(hk0, w, acc0[o]);
        acc1[o] = fmaf(hk1, w, acc1[o]);
      }
    }
#pragma unroll
    for (int o = 0; o < 32; ++o)
      m[o] = fmaxf(fmaxf(m[o], acc0[o]), acc1[o]);         // tile order, exact
    __syncthreads();                                       // h2t reuse guard
  }

#pragma unroll
  for (int off = 32; off > 0; off >>= 1) {
#pragma unroll
    for (int o = 0; o < 32; ++o) m[o] = fmaxf(m[o], __shfl_xor(m[o], off, 64));
  }
  if (lane == 0) {
    unsigned* __restrict__ hr = henc + b * 512 + wv * 32;
#pragma unroll
    for (int o = 0; o < 32; ++o) atomicMax(hr + o, __float_as_uint(m[o]));
  }
}

// ---------------------------------------------------------------------------
// Fast f64 exp (Cody-Waite + degree-13 Taylor, exact 1/k! coeffs, branch-
// free, ~1 ulp for |x| < 700). Perturbs vs libm at ~1e-16 rel -> invisible
// at f32 output rounding (f64-perturbation invariance proven rounds 4-7).
// ---------------------------------------------------------------------------
__device__ __forceinline__ double fexp(double x) {
  const double n = rint(x * 1.44269504088896338700e+00);
  const double r = fma(-n, 1.90821492927058770002e-10,
                       fma(-n, 6.93147180369123816490e-01, x));
  double p = 1.0 / 6227020800.0;                 // 1/13!
  p = fma(p, r, 1.0 / 479001600.0);
  p = fma(p, r, 1.0 / 39916800.0);
  p = fma(p, r, 1.0 / 3628800.0);
  p = fma(p, r, 1.0 / 362880.0);
  p = fma(p, r, 1.0 / 40320.0);
  p = fma(p, r, 1.0 / 5040.0);
  p = fma(p, r, 1.0 / 720.0);
  p = fma(p, r, 1.0 / 120.0);
  p = fma(p, r, 1.0 / 24.0);
  p = fma(p, r, 1.0 / 6.0);
  p = fma(p, r, 0.5);
  p = fma(p, r, 1.0);
  p = fma(p, r, 1.0);
  return ldexp(p, (int)n);
}
__device__ __forceinline__ double fsigm(double x) { return 1.0 / (1.0 + fexp(-x)); }
__device__ __forceinline__ double ftanh(double y) {
  const double e = fexp(-2.0 * y);
  return (1.0 - e) / (1.0 + e);
}

// ---------------------------------------------------------------------------
// global->LDS async DMA (zero-VGPR prefetch path). LDS dst = wave-uniform
// base + lane*16; global src = per-lane addr. Counted by vmcnt; retires in
// issue order -> counted s_waitcnt gives exact chunk-granular sync.
// ---------------------------------------------------------------------------
typedef __attribute__((address_space(1))) unsigned int gls_gt;
typedef __attribute__((address_space(3))) unsigned int gls_lt;
__device__ __forceinline__ void dma16(const float* g, float* l) {
  __builtin_amdgcn_global_load_lds((gls_gt*)g, (gls_lt*)l, 16, 0, 0);
}

// ---------------------------------------------------------------------------
// GRU rollout, f64. Round-21 = round-12's DMA-pipeline with the RACE FIXED.
// R12 failed absmax 5.5e-05: STG(i+5) rewrote the buffer consumed by CNS(i)
// in the same iteration; an ISSUED ds_read can physically execute hundreds
// of cycles later (DS-queue contention) -- after the DMA return (~200cy)
// overwrote the buffer. FIX: s_waitcnt lgkmcnt(0) + sched_barrier(0) BEFORE
// each STG -> the wave's ds_reads are architecturally complete (data in
// VGPRs) before the overwriting DMA is issued. Cost ~0 (FMAs needed those
// values via lgkmcnt anyway). Order: CNS_LD (vmcnt-wait + ds_read) -> STG
// (lgkm-drain + 3 DMAs) -> CNS_FMA (12 f64 FMA, exact R4 order).
// Everything else identical to R12: grid 256, block 576, 2 barriers/step,
// 5-buf x 1-k4 ring/wave, vmcnt(12), ow1/ow2 from global in slack wave 8.
// ---------------------------------------------------------------------------
__global__ __launch_bounds__(576) void gru_kernel(
    const float* __restrict__ henc,     // [256][512] (maxpool bits)
    const float* __restrict__ mw1, const float* __restrict__ mb1,
    const float* __restrict__ mw2, const float* __restrict__ mb2,
    const float* __restrict__ mw3, const float* __restrict__ mb3,
    const float* __restrict__ wih, const float* __restrict__ wp,
    const float* __restrict__ bih, const float* __restrict__ bhh,
    const float* __restrict__ ow1, const float* __restrict__ ob1,
    const float* __restrict__ ow2, const float* __restrict__ ob2,
    const float* __restrict__ ow3, const float* __restrict__ ob3,
    float* __restrict__ dout) {
  __shared__ __align__(16) float stage_f[30720];  // 8 waves x 5 bufs x 768 f
  __shared__ __align__(16) double h_l[256];       // single sample
  __shared__ double pp[3][256];                   // half1 partials [gate][c]
  __shared__ float wihf[4608];
  __shared__ float bihf[768];
  __shared__ float ow3f[384];
  __shared__ double o1_l[64];
  __shared__ double o2_l[64];
  __shared__ double gia_l[6];

  const int t = threadIdx.x;
  const int s = blockIdx.x;                     // sample

  for (int i = t; i < 4608; i += 576) wihf[i] = wih[i];
  for (int i = t; i < 768; i += 576) bihf[i] = bih[i];
  if (t < 384) ow3f[t] = ow3[t];

  double* const g1_l = (double*)stage_f;        // 256 doubles (phase 0 only)
  double* const g2_l = (double*)stage_f + 256;  // 128 doubles (phase 0 only)

  // ---- phase 0: gru_h init MLP (512->256->128->256), f64 (R4 verbatim) --
  if (t < 256) {
    const float* __restrict__ hrow = henc + (s << 9);
    double a = (double)mb1[t];
#pragma unroll 4
    for (int k = 0; k < 512; ++k)
      a = fma((double)hrow[k], (double)mw1[k * 256 + t], a);
    g1_l[t] = fmax(a, 0.0);
  }
  __syncthreads();
  if (t < 128) {
    double a = (double)mb2[t];
#pragma unroll 4
    for (int k = 0; k < 256; ++k) a = fma(g1_l[k], (double)mw2[k * 128 + t], a);
    g2_l[t] = fmax(a, 0.0);
  }
  __syncthreads();
  if (t < 256) {
    double a = (double)mb3[t];
#pragma unroll 4
    for (int k = 0; k < 128; ++k) a = fma(g2_l[k], (double)mw3[k * 256 + t], a);
    h_l[t] = a;
  }
  if (t < 6) gia_l[t] = 0.0;
  __syncthreads();                    // phase-0 done; stage region free

  // ---- thread constants ----
  const int c = t & 255;
  const int hh = (t >> 8) & 1;                 // k-half (t<512)
  const int khome = hh << 5;                   // k4 range [khome, khome+32)
  const int w = t >> 6;                        // wave id 0..8
  const int lane = t & 63;
  const int cbase = (w & 3) << 6;              // wave's channel base
  float* const swv = stage_f + w * 3840;       // wave's 5-buf stage region
  const double br = (t < 512 && hh == 0) ? (double)bhh[c] : 0.0;
  const double bz = (t < 512 && hh == 0) ? (double)bhh[256 + c] : 0.0;
  const double bn = (t < 512 && hh == 0) ? (double)bhh[512 + c] : 0.0;
  double hreg = (t < 256) ? h_l[c] : 0.0;      // own phase-0 write

  // out_mlp constants (wave 8)
  const int ln = t & 63;
  double ob1d = 0.0, ob2d = 0.0, ob3d = 0.0;
  if (t >= 512) {
    ob1d = (double)ob1[ln];
    ob2d = (double)ob2[ln];
    if (ln < 6) ob3d = (double)ob3[ln];
  }

  double ar, az, an;
  float4 wr4, wz4, wn4;
  int acnt = 0, bcv = 0;     // absolute chunk counter / ring buffer index

  // load the consumed chunk's weights from ring buffer BUF into wr4/wz4/wn4
#define CNS_LD(BUF) {                                                        \
    asm volatile("s_waitcnt vmcnt(12)" ::: "memory");                        \
    __builtin_amdgcn_sched_barrier(0);                                       \
    const float* lb = swv + (BUF) * 768 + (lane << 2);                       \
    wr4 = *(const float4*)(lb);                                              \
    wz4 = *(const float4*)(lb + 256);                                        \
    wn4 = *(const float4*)(lb + 512);                                        \
  }

  // stage one k4 chunk (3 gates x 1KB) into ring buffer BUF.
  // lgkmcnt(0) first: all prior ds_reads architecturally complete -> the
  // DMA (which lands >=~200cy after issue) cannot overwrite unread data.
#define STG(K4, BUF) {                                                       \
    asm volatile("s_waitcnt lgkmcnt(0)" ::: "memory");                       \
    __builtin_amdgcn_sched_barrier(0);                                       \
    const float* gp = wp + (((K4) * 768 + cbase + lane) << 2);               \
    float* lp = swv + (BUF) * 768;                                           \
    dma16(gp, lp);                                                           \
    dma16(gp + 1024, lp + 256);                                              \
    dma16(gp + 2048, lp + 512);                                              \
  }

  // FMA order identical to R4's MV_K (bit-identical output)
#define CNS_FMA(K4) {                                                        \
    const double2 ha = *(const double2*)(h_l + ((K4) << 2));                 \
    const double2 hb = *(const double2*)(h_l + ((K4) << 2) + 2);             \
    ar = fma(ha.x, (double)wr4.x, ar); ar = fma(ha.y, (double)wr4.y, ar);    \
    ar = fma(hb.x, (double)wr4.z, ar); ar = fma(hb.y, (double)wr4.w, ar);    \
    az = fma(ha.x, (double)wz4.x, az); az = fma(ha.y, (double)wz4.y, az);    \
    az = fma(hb.x, (double)wz4.z, az); az = fma(hb.y, (double)wz4.w, az);    \
    an = fma(ha.x, (double)wn4.x, an); an = fma(ha.y, (double)wn4.y, an);    \
    an = fma(hb.x, (double)wn4.z, an); an = fma(hb.y, (double)wn4.w, an);    \
  }

  // one pipelined 32-k4 pass; tail issues reach into the next pass (same
  // weights every step -> wrap (a+5)&31). acnt/bcv persist across passes.
#define MV_PASS() {                                                          \
    _Pragma("unroll 1")                                                      \
    for (int ci = 0; ci < 32; ++ci) {                                        \
      const int a_ = acnt + ci;                                              \
      CNS_LD(bcv)                                                            \
      STG(khome + ((a_ + 5) & 31), bcv)                                      \
      CNS_FMA(khome + (a_ & 31))                                             \
      bcv = (bcv == 4) ? 0 : bcv + 1;                                        \
    }                                                                        \
    acnt += 32;                                                              \
  }

  // ---- prologue: fill ring, then both halves' partials of comb(h0) ----
  if (t < 512) {
    STG(khome + 0, 0) STG(khome + 1, 1) STG(khome + 2, 2)
    STG(khome + 3, 3) STG(khome + 4, 4)
    ar = br; az = bz; an = bn;
    MV_PASS()
    if (hh) { pp[0][c] = ar; pp[1][c] = az; pp[2][c] = an; }
  }
  __syncthreads();                    // pp visible; drains in-flight stages

#pragma unroll 1
  for (int step = 0; step < T_; ++step) {
    // ---- gates (t<256): comb = own half0 (biased) + half1 from pp ----
    if (t < 256) {
      const double cr = ar + pp[0][c];
      const double cz = az + pp[1][c];
      const double cn = an + pp[2][c];
      double gr = (double)bihf[c], gz = (double)bihf[256 + c],
             gn = (double)bihf[512 + c];
#pragma unroll
      for (int a = 0; a < 6; ++a) {
        const double xa = gia_l[a];
        gr = fma((double)wihf[c * 6 + a], xa, gr);
        gz = fma((double)wihf[(256 + c) * 6 + a], xa, gz);
        gn = fma((double)wihf[(512 + c) * 6 + a], xa, gn);
      }
      const double rv = fsigm(cr + gr);
      const double zv = fsigm(cz + gz);
      const double nv = ftanh(fma(rv, cn, gn));
      hreg = fma(zv, hreg - nv, nv);
      h_l[c] = hreg;
    }
    if (t < 512) { ar = br; az = bz; an = bn; }
    __syncthreads();                  // [A] h published; stages drained

    if (t < 512) {
      // ---- matvec: DMA-pipelined 32-k4 pass (zero-VGPR prefetch) ----
      MV_PASS()
      if (hh) { pp[0][c] = ar; pp[1][c] = az; pp[2][c] = an; }
    } else {
      // ---- out_mlp, wave-private (wave 8); ow1/ow2 from global ----
      double a0 = ob1d, a1 = 0.0;     // (ob1 + asc lo) + (asc hi): proven assoc
#pragma unroll 4
      for (int k = 0; k < 128; ++k) {
        a0 = fma(h_l[k], (double)ow1[k * 64 + ln], a0);
        a1 = fma(h_l[128 + k], (double)ow1[(128 + k) * 64 + ln], a1);
      }
      o1_l[ln] = fmax(a0 + a1, 0.0);
      __builtin_amdgcn_wave_barrier();                    // own-wave LDS only
      double b0 = ob2d;
#pragma unroll 4
      for (int k = 0; k < 64; ++k)
        b0 = fma(o1_l[k], (double)ow2[k * 64 + ln], b0);
      o2_l[ln] = fmax(b0, 0.0);
      __builtin_amdgcn_wave_barrier();
      if (ln < 6) {
        double a = ob3d;
#pragma unroll 4
        for (int k = 0; k < 64; ++k)
          a = fma(o2_l[k], (double)ow3f[k * 6 + ln], a);
        const double gi_new = gia_l[ln] + a;
        gia_l[ln] = gi_new;
        dout[s * 300 + step * 6 + ln] = (float)a;              // dws
        dout[76800 + s * 300 + step * 6 + ln] = (float)gi_new; // ws
      }
    }
    __syncthreads();                  // [B] pp + gia ready; drains stages
  }
#undef CNS_LD
#undef STG
#undef CNS_FMA
#undef MV_PASS
}

extern "C" void kernel_launch(void* const* d_in, const int* in_sizes, int n_in,
                              void* d_out, int out_size, void* d_ws, size_t ws_size,
                              hipStream_t stream) {
  const float* data = (const float*)d_in[0];
  // d_in[1] = horizon (always 50)
  const float* ew1 = (const float*)d_in[2];
  const float* eb1 = (const float*)d_in[3];
  const float* ew2 = (const float*)d_in[4];
  const float* eb2 = (const float*)d_in[5];
  const float* ew3 = (const float*)d_in[6];
  const float* eb3 = (const float*)d_in[7];
  const float* mw1 = (const float*)d_in[8];
  const float* mb1 = (const float*)d_in[9];
  const float* mw2 = (const float*)d_in[10];
  const float* mb2 = (const float*)d_in[11];
  const float* mw3 = (const float*)d_in[12];
  const float* mb3 = (const float*)d_in[13];
  const float* wih = (const float*)d_in[14];
  const float* whh = (const float*)d_in[15];
  const float* bih = (const float*)d_in[16];
  const float* bhh = (const float*)d_in[17];
  const float* ow1 = (const float*)d_in[18];
  const float* ob1 = (const float*)d_in[19];
  const float* ow2 = (const float*)d_in[20];
  const float* ob2 = (const float*)d_in[21];
  const float* ow3 = (const float*)d_in[22];
  const float* ob3 = (const float*)d_in[23];
  float* out = (float*)d_out;

  char* ws = (char*)d_ws;
  float*    wp   = (float*)(ws);                 // 786432 B
  unsigned* henc = (unsigned*)(ws + 786432);     // 524288 B -> end 1310720

  prep_kernel<<<768, 256, 0, stream>>>(whh, wp, henc);
  enc_kernel<<<512, 1024, 0, stream>>>(data, ew1, eb1, ew2, eb2, ew3, eb3, henc);
  gru_kernel<<<256, 576, 0, stream>>>((const float*)henc,
                                      mw1, mb1, mw2, mb2, mw3, mb3,
                                      wih, wp, bih, bhh,
                                      ow1, ob1, ow2, ob2, ow3, ob3,
                                      out);
}

// Round 14
// 1137.450 us; speedup vs baseline: 1.1213x; 1.1213x over previous
//
#include <hip/hip_runtime.h>
#include <math.h>

// Problem constants
#define B_    256
#define NPTS  1024
#define T_    50

// ---------------------------------------------------------------------------
// ws layout (bytes):
//   [0,       786432)   wp   f32 [64][3][256][4]  packed W_hh (round-7 layout)
//   [786432,  1310720)  henc u32 [256][512]       (f32-bit maxpool via atomicMax)
// ---------------------------------------------------------------------------

__global__ __launch_bounds__(256) void prep_kernel(
    const float* __restrict__ whh, float* __restrict__ wp,
    unsigned* __restrict__ henc) {
  int idx = blockIdx.x * 256 + threadIdx.x;   // grid 768*256 = 196608
  if (idx < 196608) {
    int c = idx & 3;
    int r = idx >> 2;            // (k4*3+j)*256 + t
    int t2 = r & 255;
    int q = r >> 8;              // k4*3 + j
    int j = q % 3;
    int k4 = q / 3;
    wp[idx] = whh[(j * 256 + t2) * 256 + (k4 * 4 + c)];
  }
  if (idx < 131072) henc[idx] = 0u;           // bits 0 == +0.0f; relu>=0 valid
}

// ---------------------------------------------------------------------------
// Encoder. Round-22 = R11's 2-tile structure + PHASE-1 PAIRING: both tiles
// of a pair computed in ONE j-loop sharing each w1[j]/b1[j]/w2r[c] s_load
// (R11 only dedup'd phase-2's w3). Phase-1 scalar traffic and lgkm-stall
// exposure halve -- the same mechanism that paid -65us in R11's phase-2.
// Per-accumulator FMA order identical per tile (same values, same ascending
// j/k sequences) -> output bit-identical. gru stream theory closed (R13):
// gru reverted to the R4 650us winner and frozen.
// ---------------------------------------------------------------------------
__global__ __launch_bounds__(1024) void enc_kernel(
    const float* __restrict__ data,
    const float* __restrict__ w1, const float* __restrict__ b1,
    const float* __restrict__ w2, const float* __restrict__ b2,
    const float* __restrict__ w3, const float* __restrict__ b3,
    unsigned* __restrict__ henc) {
  __shared__ float h2t[2][128][66];
  const int t = threadIdx.x;
  const int b = blockIdx.x >> 1;
  const int half = blockIdx.x & 1;
  const int lane = t & 63;
  const int wv = __builtin_amdgcn_readfirstlane(t >> 6);   // wave id 0..15

  float m[32];
#pragma unroll
  for (int o = 0; o < 32; ++o) m[o] = 0.0f;                // relu via max w/ 0
  const float* __restrict__ w3b = w3 + wv * 32;

#pragma unroll 1
  for (int pair = 0; pair < 4; ++pair) {
    {
      // ---- phase 1, paired: one w1/w2 s_load stream feeds BOTH tiles ----
      const int ptg = b * NPTS + half * 512 + pair * 128 + lane;
      const float x00 = data[ptg * 3], x01 = data[ptg * 3 + 1],
                  x02 = data[ptg * 3 + 2];
      const float x10 = data[(ptg + 64) * 3], x11 = data[(ptg + 64) * 3 + 1],
                  x12 = data[(ptg + 64) * 3 + 2];
      float a0[8], a1[8];
#pragma unroll
      for (int c = 0; c < 8; ++c) { a0[c] = b2[wv * 8 + c]; a1[c] = a0[c]; }
#pragma unroll 4
      for (int j = 0; j < 64; ++j) {                       // w1/b1 uniform
        const float w1a = w1[j], w1b = w1[64 + j], w1c = w1[128 + j];
        const float b1j = b1[j];
        float hj0 = fmaf(x00, w1a, fmaf(x01, w1b, fmaf(x02, w1c, b1j)));
        hj0 = fmaxf(hj0, 0.0f);
        float hj1 = fmaf(x10, w1a, fmaf(x11, w1b, fmaf(x12, w1c, b1j)));
        hj1 = fmaxf(hj1, 0.0f);
        const float* __restrict__ w2r = w2 + j * 128 + wv * 8;  // s_load x8
#pragma unroll
        for (int c = 0; c < 8; ++c) {
          const float wv2 = w2r[c];
          a0[c] = fmaf(hj0, wv2, a0[c]);
          a1[c] = fmaf(hj1, wv2, a1[c]);
        }
      }
#pragma unroll
      for (int c = 0; c < 8; ++c) {
        h2t[0][wv * 8 + c][lane] = fmaxf(a0[c], 0.0f);
        h2t[1][wv * 8 + c][lane] = fmaxf(a1[c], 0.0f);
      }
    }
    __syncthreads();

    // ---- phase 2: R11 verbatim (one w3 row feeds two acc chains) ----
    float acc0[32], acc1[32];
#pragma unroll
    for (int o = 0; o < 32; ++o) {
      acc0[o] = b3[wv * 32 + o];                           // s_load seed (R4)
      acc1[o] = acc0[o];                                   // same b3 value
    }
#pragma unroll 4
    for (int k = 0; k < 128; ++k) {
      const float hk0 = h2t[0][k][lane];                   // ds_read_b32
      const float hk1 = h2t[1][k][lane];                   // ds_read_b32
      const float* __restrict__ wr = w3b + k * 512;        // ONE s_load row
#pragma unroll
      for (int o = 0; o < 32; ++o) {
        const float w = wr[o];
        acc0[o] = fmaf(hk0, w, acc0[o]);
        acc1[o] = fmaf(hk1, w, acc1[o]);
      }
    }
#pragma unroll
    for (int o = 0; o < 32; ++o)
      m[o] = fmaxf(fmaxf(m[o], acc0[o]), acc1[o]);         // tile order, exact
    __syncthreads();                                       // h2t reuse guard
  }

#pragma unroll
  for (int off = 32; off > 0; off >>= 1) {
#pragma unroll
    for (int o = 0; o < 32; ++o) m[o] = fmaxf(m[o], __shfl_xor(m[o], off, 64));
  }
  if (lane == 0) {
    unsigned* __restrict__ hr = henc + b * 512 + wv * 32;
#pragma unroll
    for (int o = 0; o < 32; ++o) atomicMax(hr + o, __float_as_uint(m[o]));
  }
}

// ---------------------------------------------------------------------------
// Fast f64 exp (Cody-Waite + degree-13 Taylor, exact 1/k! coeffs, branch-
// free, ~1 ulp for |x| < 700). Perturbs vs libm at ~1e-16 rel -> invisible
// at f32 output rounding (f64-perturbation invariance proven rounds 4-7).
// ---------------------------------------------------------------------------
__device__ __forceinline__ double fexp(double x) {
  const double n = rint(x * 1.44269504088896338700e+00);
  const double r = fma(-n, 1.90821492927058770002e-10,
                       fma(-n, 6.93147180369123816490e-01, x));
  double p = 1.0 / 6227020800.0;                 // 1/13!
  p = fma(p, r, 1.0 / 479001600.0);
  p = fma(p, r, 1.0 / 39916800.0);
  p = fma(p, r, 1.0 / 3628800.0);
  p = fma(p, r, 1.0 / 362880.0);
  p = fma(p, r, 1.0 / 40320.0);
  p = fma(p, r, 1.0 / 5040.0);
  p = fma(p, r, 1.0 / 720.0);
  p = fma(p, r, 1.0 / 120.0);
  p = fma(p, r, 1.0 / 24.0);
  p = fma(p, r, 1.0 / 6.0);
  p = fma(p, r, 0.5);
  p = fma(p, r, 1.0);
  p = fma(p, r, 1.0);
  return ldexp(p, (int)n);
}
__device__ __forceinline__ double fsigm(double x) { return 1.0 / (1.0 + fexp(-x)); }
__device__ __forceinline__ double ftanh(double y) {
  const double e = fexp(-2.0 * y);
  return (1.0 - e) / (1.0 + e);
}

// ---------------------------------------------------------------------------
// GRU rollout, f64 -- ROUND-4 WINNER VERBATIM (650us steady), FROZEN.
// grid 256, block 576 (9 waves), 2 barriers/step, plain unroll-2 JIT loads,
// wave-8 concurrent wave-private out_mlp. The wp stream (~25-30 B/cy/CU) is
// a structural ceiling: invariant to waves (R5), unroll/nt (R7), XCD demand
// (R8); register prefetch spills (R2/R3/R9); LDS-DMA pipeline is correct
// but slower (R13: 805us, wait/addressing overhead > latency hidden).
// ---------------------------------------------------------------------------
__global__ __launch_bounds__(576) void gru_kernel(
    const float* __restrict__ henc,     // [256][512] (maxpool bits)
    const float* __restrict__ mw1, const float* __restrict__ mb1,
    const float* __restrict__ mw2, const float* __restrict__ mb2,
    const float* __restrict__ mw3, const float* __restrict__ mb3,
    const float* __restrict__ wih, const float* __restrict__ wp,
    const float* __restrict__ bih, const float* __restrict__ bhh,
    const float* __restrict__ ow1, const float* __restrict__ ob1,
    const float* __restrict__ ow2, const float* __restrict__ ob2,
    const float* __restrict__ ow3, const float* __restrict__ ob3,
    float* __restrict__ dout) {
  __shared__ __align__(16) double h_l[256];     // single sample
  __shared__ double pp[3][256];                 // half1 partials [gate][c]
  __shared__ __align__(16) float ow1f[16384];   // phase-0 alias: g1(256d)+g2(128d)
  __shared__ __align__(16) float ow2f[4096];
  __shared__ float ow3f[384];
  __shared__ float wihf[4608];
  __shared__ float bihf[768];
  __shared__ double o1_l[64];
  __shared__ double o2_l[64];
  __shared__ double gia_l[6];

  const int t = threadIdx.x;
  const int s = blockIdx.x;                     // sample

  for (int i = t; i < 4608; i += 576) wihf[i] = wih[i];
  for (int i = t; i < 768; i += 576) bihf[i] = bih[i];

  double* const g1_l = (double*)ow1f;           // 256 doubles (phase 0 only)
  double* const g2_l = (double*)ow1f + 256;     // 128 doubles (phase 0 only)

  // ---- phase 0: gru_h init MLP (512->256->128->256), f64 (round-7 math) --
  if (t < 256) {
    const float* __restrict__ hrow = henc + (s << 9);
    double a = (double)mb1[t];
#pragma unroll 4
    for (int k = 0; k < 512; ++k)
      a = fma((double)hrow[k], (double)mw1[k * 256 + t], a);
    g1_l[t] = fmax(a, 0.0);
  }
  __syncthreads();
  if (t < 128) {
    double a = (double)mb2[t];
#pragma unroll 4
    for (int k = 0; k < 256; ++k) a = fma(g1_l[k], (double)mw2[k * 128 + t], a);
    g2_l[t] = fmax(a, 0.0);
  }
  __syncthreads();
  if (t < 256) {
    double a = (double)mb3[t];
#pragma unroll 4
    for (int k = 0; k < 128; ++k) a = fma(g2_l[k], (double)mw3[k * 256 + t], a);
    h_l[t] = a;
  }
  if (t < 6) gia_l[t] = 0.0;
  __syncthreads();                    // phase-0 reads of g1/g2 complete

  // ---- stage out_mlp f32 weights into LDS (overwrites g1/g2 region) ----
  for (int i = t; i < 16384; i += 576) ow1f[i] = ow1[i];
  for (int i = t; i < 4096; i += 576) ow2f[i] = ow2[i];
  if (t < 384) ow3f[t] = ow3[t];
  // (visible to wave 8 after the post-prologue __syncthreads)

  // ---- thread constants ----
  const int c = t & 255;
  const int hh = (t >> 8) & 1;                 // k-half (t<512)
  const int khome = hh << 5;                   // k4 range [khome, khome+32)
  const double br = (t < 512 && hh == 0) ? (double)bhh[c] : 0.0;
  const double bz = (t < 512 && hh == 0) ? (double)bhh[256 + c] : 0.0;
  const double bn = (t < 512 && hh == 0) ? (double)bhh[512 + c] : 0.0;
  double hreg = (t < 256) ? h_l[c] : 0.0;      // own phase-0 write
  const float* const wpc = wp + c * 4;

  // out_mlp constants (wave 8)
  const int ln = t & 63;
  double ob1d = 0.0, ob2d = 0.0, ob3d = 0.0;
  if (t >= 512) {
    ob1d = (double)ob1[ln];
    ob2d = (double)ob2[ln];
    if (ln < 6) ob3d = (double)ob3[ln];
  }

  double ar, az, an;

  // FMA order per k4 identical to round-0's per-sample chain:
  // ar: ha.x,ha.y,hb.x,hb.y then az x4 then an x4, k4 ascending.
#define MV_K(kk) {                                                           \
    const float* p_ = wpc + (khome + (kk)) * 3072;                           \
    const float4 wr = *(const float4*)(p_);                                  \
    const float4 wz = *(const float4*)(p_ + 1024);                           \
    const float4 wn = *(const float4*)(p_ + 2048);                           \
    const double2 ha = *(const double2*)(h_l + ((khome + (kk)) << 2));       \
    const double2 hb = *(const double2*)(h_l + ((khome + (kk)) << 2) + 2);   \
    ar = fma(ha.x, (double)wr.x, ar); ar = fma(ha.y, (double)wr.y, ar);      \
    ar = fma(hb.x, (double)wr.z, ar); ar = fma(hb.y, (double)wr.w, ar);      \
    az = fma(ha.x, (double)wz.x, az); az = fma(ha.y, (double)wz.y, az);      \
    az = fma(hb.x, (double)wz.z, az); az = fma(hb.y, (double)wz.w, az);      \
    an = fma(ha.x, (double)wn.x, an); an = fma(ha.y, (double)wn.y, an);      \
    an = fma(hb.x, (double)wn.z, an); an = fma(hb.y, (double)wn.w, an);      \
  }

  // ---- prologue: both halves' partials of comb(h0) ----
  if (t < 512) {
    ar = br; az = bz; an = bn;
#pragma unroll 2
    for (int kk = 0; kk < 32; ++kk) MV_K(kk)
    if (hh) { pp[0][c] = ar; pp[1][c] = az; pp[2][c] = an; }
  }
  __syncthreads();                    // pp + staged LDS weights visible

#pragma unroll 1
  for (int step = 0; step < T_; ++step) {
    // ---- gates (t<256): comb = own half0 (biased) + half1 from pp ----
    if (t < 256) {
      const double cr = ar + pp[0][c];
      const double cz = az + pp[1][c];
      const double cn = an + pp[2][c];
      double gr = (double)bihf[c], gz = (double)bihf[256 + c],
             gn = (double)bihf[512 + c];
#pragma unroll
      for (int a = 0; a < 6; ++a) {
        const double xa = gia_l[a];
        gr = fma((double)wihf[c * 6 + a], xa, gr);
        gz = fma((double)wihf[(256 + c) * 6 + a], xa, gz);
        gn = fma((double)wihf[(512 + c) * 6 + a], xa, gn);
      }
      const double rv = fsigm(cr + gr);
      const double zv = fsigm(cz + gz);
      const double nv = ftanh(fma(rv, cn, gn));
      hreg = fma(zv, hreg - nv, nv);
      h_l[c] = hreg;
    }
    if (t < 512) { ar = br; az = bz; an = bn; }
    __syncthreads();                  // [A] h published

    if (t < 512) {
      // ---- matvec: one plain 32-k4 pass (compiler-scheduled loads) ----
#pragma unroll 2
      for (int kk = 0; kk < 32; ++kk) MV_K(kk)
      if (hh) { pp[0][c] = ar; pp[1][c] = az; pp[2][c] = an; }
    } else {
      // ---- out_mlp, wave-private (wave 8) ----
      double a0 = ob1d, a1 = 0.0;     // (ob1 + asc lo) + (asc hi): proven assoc
#pragma unroll 4
      for (int k = 0; k < 128; ++k) {
        a0 = fma(h_l[k], (double)ow1f[k * 64 + ln], a0);
        a1 = fma(h_l[128 + k], (double)ow1f[(128 + k) * 64 + ln], a1);
      }
      o1_l[ln] = fmax(a0 + a1, 0.0);
      __builtin_amdgcn_wave_barrier();                    // own-wave LDS only
      double b0 = ob2d;
#pragma unroll 4
      for (int k = 0; k < 64; ++k)
        b0 = fma(o1_l[k], (double)ow2f[k * 64 + ln], b0);
      o2_l[ln] = fmax(b0, 0.0);
      __builtin_amdgcn_wave_barrier();
      if (ln < 6) {
        double a = ob3d;
#pragma unroll 4
        for (int k = 0; k < 64; ++k)
          a = fma(o2_l[k], (double)ow3f[k * 6 + ln], a);
        const double gi_new = gia_l[ln] + a;
        gia_l[ln] = gi_new;
        dout[s * 300 + step * 6 + ln] = (float)a;              // dws
        dout[76800 + s * 300 + step * 6 + ln] = (float)gi_new; // ws
      }
    }
    __syncthreads();                  // [B] pp + gia ready for next gates
  }
#undef MV_K
}

extern "C" void kernel_launch(void* const* d_in, const int* in_sizes, int n_in,
                              void* d_out, int out_size, void* d_ws, size_t ws_size,
                              hipStream_t stream) {
  const float* data = (const float*)d_in[0];
  // d_in[1] = horizon (always 50)
  const float* ew1 = (const float*)d_in[2];
  const float* eb1 = (const float*)d_in[3];
  const float* ew2 = (const float*)d_in[4];
  const float* eb2 = (const float*)d_in[5];
  const float* ew3 = (const float*)d_in[6];
  const float* eb3 = (const float*)d_in[7];
  const float* mw1 = (const float*)d_in[8];
  const float* mb1 = (const float*)d_in[9];
  const float* mw2 = (const float*)d_in[10];
  const float* mb2 = (const float*)d_in[11];
  const float* mw3 = (const float*)d_in[12];
  const float* mb3 = (const float*)d_in[13];
  const float* wih = (const float*)d_in[14];
  const float* whh = (const float*)d_in[15];
  const float* bih = (const float*)d_in[16];
  const float* bhh = (const float*)d_in[17];
  const float* ow1 = (const float*)d_in[18];
  const float* ob1 = (const float*)d_in[19];
  const float* ow2 = (const float*)d_in[20];
  const float* ob2 = (const float*)d_in[21];
  const float* ow3 = (const float*)d_in[22];
  const float* ob3 = (const float*)d_in[23];
  float* out = (float*)d_out;

  char* ws = (char*)d_ws;
  float*    wp   = (float*)(ws);                 // 786432 B
  unsigned* henc = (unsigned*)(ws + 786432);     // 524288 B -> end 1310720

  prep_kernel<<<768, 256, 0, stream>>>(whh, wp, henc);
  enc_kernel<<<512, 1024, 0, stream>>>(data, ew1, eb1, ew2, eb2, ew3, eb3, henc);
  gru_kernel<<<256, 576, 0, stream>>>((const float*)henc,
                                      mw1, mb1, mw2, mb2, mw3, mb3,
                                      wih, wp, bih, bhh,
                                      ow1, ob1, ow2, ob2, ow3, ob3,
                                      out);
}